// Round 13
// baseline (155.418 us; speedup 1.0000x reference)
//
#include <hip/hip_runtime.h>
#include <math.h>

#define BATCH 16
#define NCLS 20
#define TOPK 100
#define NPRE 1000
#define NTOT 2400
#define NBINS 8
#define N0 6400
#define N1 1600
#define SSEL 256         // candidates selected+sorted per (b,c); 4 chunks of 64

// Exact replication of RN(inter/denom) > 0.5f for positive finite floats:
// RN(x) > 0.5 <=> x > 0.5 + 2^-25 (midpoint; tie-to-even rounds DOWN to 0.5).
// (double)denom * MID05 is exact (24+26 = 50 significand bits < 53).
#define MID05 0.50000002980232238769531250

// ---- order-preserving float->uint map (ascending) ----
__device__ __forceinline__ unsigned int orderable(float x) {
    unsigned int u = __float_as_uint(x);
    return (u & 0x80000000u) ? ~u : (u | 0x80000000u);
}
__device__ __forceinline__ float unorderable(unsigned int k) {
    return __uint_as_float((k & 0x80000000u) ? (k ^ 0x80000000u) : ~k);
}

// ---- wave-local suffix-scan digit selection. hist[256] ready; lane l owns
// bins 4l..4l+3. Picks the unique digit d with sfx[d] >= kk > sfx[d+1].
// Caller guards lane < 64 and passes a full wave. ----
__device__ __forceinline__ void radix_pass_scan(
        const unsigned int* hist, unsigned int* s_prefix, unsigned int* s_kk,
        unsigned int prefix, unsigned int kk, int lane) {
    uint4 h = *(const uint4*)&hist[lane * 4];
    unsigned int s3 = h.w;
    unsigned int s2 = h.z + s3;
    unsigned int s1 = h.y + s2;
    unsigned int s0 = h.x + s1;          // lane-local suffix sums
    unsigned int S = s0;
    #pragma unroll
    for (int off = 1; off < 64; off <<= 1) {
        unsigned int o = __shfl_down(S, off);
        S += (lane + off < 64) ? o : 0u;
    }
    unsigned int Sgt = S - s0;           // sum over lanes > lane
    unsigned int F0 = s0 + Sgt, F1 = s1 + Sgt, F2 = s2 + Sgt, F3 = s3 + Sgt;
    if (F0 >= kk && F1 < kk)  { *s_prefix = (prefix << 8) | (unsigned int)(lane * 4 + 0); *s_kk = kk - F1; }
    if (F1 >= kk && F2 < kk)  { *s_prefix = (prefix << 8) | (unsigned int)(lane * 4 + 1); *s_kk = kk - F2; }
    if (F2 >= kk && F3 < kk)  { *s_prefix = (prefix << 8) | (unsigned int)(lane * 4 + 2); *s_kk = kk - F3; }
    if (F3 >= kk && Sgt < kk) { *s_prefix = (prefix << 8) | (unsigned int)(lane * 4 + 3); *s_kk = kk - Sgt; }
}

// ---- bitonic merge strides jmax..1 via shfl_xor (intra-wave, no barriers).
// pos is the element position within the sorted array (bit patterns). ----
__device__ __forceinline__ unsigned long long bmerge_shfl(
        unsigned long long v, int pos, int k2, int jmax) {
    for (int j2 = jmax; j2 > 0; j2 >>= 1) {
        unsigned long long o = __shfl_xor(v, j2);
        bool km = (((pos & k2) == 0) == ((pos & j2) != 0));
        v = km ? (v > o ? v : o) : (v < o ? v : o);
    }
    return v;
}

// ============================================================
// Kernel 0: per-anchor key = orderable(max_c logit). Wide grid ->
// full HBM BW on the 10.2 MB logit read. Also zeroes epilogue counters.
// ============================================================
__global__ __launch_bounds__(256) void compute_keys_kernel(
        const float* __restrict__ cls0, const float* __restrict__ cls1,
        unsigned int* __restrict__ keys0, unsigned int* __restrict__ keys1,
        int* __restrict__ cnt) {
    int tg = blockIdx.x * 256 + threadIdx.x;
    if (blockIdx.x == 0 && threadIdx.x < BATCH) cnt[threadIdx.x] = 0;
    const float* p;
    unsigned int* dst;
    if (tg < BATCH * N0) {
        p = cls0 + (size_t)tg * NCLS;
        dst = keys0 + tg;
    } else {
        int a = tg - BATCH * N0;
        if (a >= BATCH * N1) return;
        p = cls1 + (size_t)a * NCLS;
        dst = keys1 + a;
    }
    const float4* p4 = (const float4*)p;
    float m = -INFINITY;
    #pragma unroll
    for (int q = 0; q < 5; ++q) {
        float4 v = p4[q];
        m = fmaxf(m, fmaxf(fmaxf(v.x, v.y), fmaxf(v.z, v.w)));
    }
    *dst = orderable(m);
}

// ============================================================
// Kernel 1: per (batch, level) exact top-1000 radix select (4 B/anchor).
// ============================================================
__global__ __launch_bounds__(256) void radix_select_kernel(
        const unsigned int* __restrict__ keys0, const unsigned int* __restrict__ keys1,
        int* __restrict__ sel_idx) {
    int bid = blockIdx.x;            // 0..31
    int b = bid >> 1;
    int lvl = bid & 1;
    int n = (lvl == 0) ? N0 : N1;
    const unsigned int* gk = (lvl == 0 ? keys0 : keys1) + (size_t)b * n;

    __shared__ unsigned int skey[N0];
    __shared__ __align__(16) unsigned int hist[256];
    __shared__ int eq[256];
    __shared__ unsigned int s_prefix, s_kk, s_cnt, s_eqcnt;
    int t = threadIdx.x;

    for (int a = t; a < n; a += 256) skey[a] = gk[a];
    if (t == 0) { s_kk = NPRE; s_prefix = 0u; s_cnt = 0u; s_eqcnt = 0u; }
    __syncthreads();

    for (int pass = 0; pass < 4; ++pass) {
        int shift = 24 - 8 * pass;
        unsigned int prefix = s_prefix, kk = s_kk;
        hist[t] = 0u;
        __syncthreads();
        for (int a = t; a < n; a += 256) {
            unsigned int u = skey[a];
            if (pass == 0 || (u >> (shift + 8)) == prefix)
                atomicAdd(&hist[(u >> shift) & 255u], 1u);
        }
        __syncthreads();
        if (t < 64) radix_pass_scan(hist, &s_prefix, &s_kk, prefix, kk, t);
        __syncthreads();
    }

    unsigned int T = s_prefix;
    int* out = sel_idx + b * 2000 + lvl * 1000;
    for (int a = t; a < n; a += 256) {
        unsigned int u = skey[a];
        if (u > T) {
            unsigned int pos = atomicAdd(&s_cnt, 1u);
            out[pos] = a;
        } else if (u == T) {
            unsigned int p = atomicAdd(&s_eqcnt, 1u);
            if (p < 256u) eq[p] = a;
        }
    }
    __syncthreads();
    if (t == 0) {
        unsigned int pos = s_cnt;
        unsigned int rem = s_kk;
        unsigned int cnt2 = s_eqcnt;
        if (cnt2 <= 256u) {
            for (unsigned int i = 1; i < cnt2; ++i) {
                int key = eq[i]; int j2 = (int)i - 1;
                while (j2 >= 0 && eq[j2] > key) { eq[j2 + 1] = eq[j2]; --j2; }
                eq[j2 + 1] = key;
            }
            for (unsigned int i = 0; i < rem; ++i) out[pos + i] = eq[i];
        } else {
            for (int a = 0; a < n && rem > 0u; ++a)
                if (skey[a] == T) { out[pos++] = a; --rem; }
        }
    }
}

// ============================================================
// Kernel 2: decode scores (sigmoid, transposed [b][c][j]) + DFL boxes.
// ============================================================
__global__ __launch_bounds__(256) void decode_kernel(
        const float* __restrict__ cls0, const float* __restrict__ cls1, const float* __restrict__ cls2,
        const float* __restrict__ bb0,  const float* __restrict__ bb1,  const float* __restrict__ bb2,
        const int* __restrict__ sel_idx,
        float* __restrict__ boxes_all, float* __restrict__ scores_t) {
    int tg = blockIdx.x * blockDim.x + threadIdx.x;
    if (tg >= BATCH * NTOT) return;
    int b = tg / NTOT, j = tg % NTOT;

    const float* cls; const float* bb; int a, w; float stride;
    if (j < 1000) {
        a = sel_idx[b * 2000 + j]; w = 80; stride = 8.f;
        cls = cls0 + ((size_t)b * N0 + a) * NCLS;
        bb  = bb0  + ((size_t)b * N0 + a) * 32;
    } else if (j < 2000) {
        a = sel_idx[b * 2000 + j]; w = 40; stride = 16.f;
        cls = cls1 + ((size_t)b * N1 + a) * NCLS;
        bb  = bb1  + ((size_t)b * N1 + a) * 32;
    } else {
        a = j - 2000; w = 20; stride = 32.f;
        cls = cls2 + ((size_t)b * 400 + a) * NCLS;
        bb  = bb2  + ((size_t)b * 400 + a) * 32;
    }

    float cl[20];
    {
        const float4* c4 = (const float4*)cls;
        #pragma unroll
        for (int q = 0; q < 5; ++q) *(float4*)&cl[q * 4] = c4[q];
    }
    float bl[32];
    {
        const float4* b4 = (const float4*)bb;
        #pragma unroll
        for (int q = 0; q < 8; ++q) *(float4*)&bl[q * 4] = b4[q];
    }

    #pragma unroll
    for (int c = 0; c < NCLS; ++c)
        scores_t[((size_t)b * NCLS + c) * NTOT + j] = 1.f / (1.f + expf(-cl[c]));

    float d[4];
    #pragma unroll
    for (int s = 0; s < 4; ++s) {
        const float* l = &bl[s * NBINS];
        float m = l[0];
        #pragma unroll
        for (int k = 1; k < NBINS; ++k) m = fmaxf(m, l[k]);
        float e[NBINS], sum = 0.f;
        #pragma unroll
        for (int k = 0; k < NBINS; ++k) { e[k] = expf(l[k] - m); sum += e[k]; }
        float acc = 0.f;
        #pragma unroll
        for (int k = 0; k < NBINS; ++k) acc += (e[k] / sum) * (float)k;
        d[s] = acc * stride;
    }
    float cy = ((float)(a / w) + 0.5f) * stride;
    float cx = ((float)(a % w) + 0.5f) * stride;
    float* bx = boxes_all + ((size_t)b * NTOT + j) * 4;
    bx[0] = fminf(fmaxf(cy - d[0], 0.f), 640.f);   // y1
    bx[1] = fminf(fmaxf(cx - d[1], 0.f), 640.f);   // x1
    bx[2] = fminf(fmaxf(cy + d[2], 0.f), 640.f);   // y2
    bx[3] = fminf(fmaxf(cx + d[3], 0.f), 640.f);   // x2
}

// ============================================================
// Kernel 3: TWO classes per 512-thread block (ci = t>>8, tl = t&255).
// 160 blocks < 256 CUs -> every block runs solo; the two classes'
// latency stalls overlap. Per-class pipeline identical to round 12.
// Last block per batch (10 blocks) runs the final top-100 epilogue.
// ============================================================
__global__ __launch_bounds__(512) void class_nms_kernel(
        const float* __restrict__ boxes_all, const float* __restrict__ scores_t,
        float* __restrict__ nms_score, int* __restrict__ nms_idx,
        int* __restrict__ cnt, float* __restrict__ outbuf) {
    int blk = blockIdx.x;                 // 0..159
    int b = blk / 10;
    int pair = blk % 10;
    int t = threadIdx.x;
    int ci = t >> 8;                      // class half 0/1
    int tl = t & 255;
    int c = pair * 2 + ci;

    __shared__ unsigned int skey[2][NTOT];          // 19200 B
    __shared__ __align__(16) unsigned int hist[2][256];  // 2048 B
    __shared__ int eq[2][128];                      // 1024 B
    __shared__ unsigned int s_prefix[2], s_kk[2], s_cnt[2], s_eqcnt[2];
    __shared__ unsigned long long sorted[2][SSEL];  // 4096 B
    __shared__ float4 abox[2][TOPK];                // 3200 B
    __shared__ float4 cbox[2][64];                  // 2048 B
    __shared__ int s_outPos[2];
    __shared__ unsigned long long s_m[2];
    __shared__ int s_last;

    const float*  ssrc = scores_t + ((size_t)b * NCLS + c) * NTOT;
    const float4* bsrc = (const float4*)boxes_all + (size_t)b * NTOT;
    float* osc = nms_score + ((size_t)b * NCLS + c) * TOPK;
    int*   oid = nms_idx   + ((size_t)b * NCLS + c) * TOPK;

    for (int j = tl; j < NTOT; j += 256) skey[ci][j] = orderable(ssrc[j]);
    if (tl == 0) { s_kk[ci] = SSEL; s_prefix[ci] = 0u; s_cnt[ci] = 0u; s_eqcnt[ci] = 0u; s_outPos[ci] = 0; }
    __syncthreads();

    // ---- phase 1a: 4-pass radix select for the SSEL-th largest key ----
    for (int pass = 0; pass < 4; ++pass) {
        int shift = 24 - 8 * pass;
        unsigned int prefix = s_prefix[ci], kk = s_kk[ci];
        hist[ci][tl] = 0u;
        __syncthreads();
        for (int j = tl; j < NTOT; j += 256) {
            unsigned int u = skey[ci][j];
            if (pass == 0 || (u >> (shift + 8)) == prefix)
                atomicAdd(&hist[ci][(u >> shift) & 255u], 1u);
        }
        __syncthreads();
        if (tl < 64)   // wave 0 (ci=0) / wave 4 (ci=1): full waves
            radix_pass_scan(hist[ci], &s_prefix[ci], &s_kk[ci], prefix, kk, tl);
        __syncthreads();
    }

    // ---- phase 1b: compact top-SSEL (ties -> lowest index, exact) ----
    unsigned int T = s_prefix[ci];
    for (int j = tl; j < NTOT; j += 256) {
        unsigned int u = skey[ci][j];
        if (u > T) {
            unsigned int pos = atomicAdd(&s_cnt[ci], 1u);
            sorted[ci][pos] = ((unsigned long long)u << 32) | (unsigned int)~j;
        } else if (u == T) {
            unsigned int p = atomicAdd(&s_eqcnt[ci], 1u);
            if (p < 128u) eq[ci][p] = j;
        }
    }
    __syncthreads();
    if (tl == 0) {
        unsigned int pos = s_cnt[ci];
        unsigned int rem = s_kk[ci];
        unsigned int cnt2 = s_eqcnt[ci];
        if (cnt2 <= 128u) {
            for (unsigned int i = 1; i < cnt2; ++i) {
                int key = eq[ci][i]; int j2 = (int)i - 1;
                while (j2 >= 0 && eq[ci][j2] > key) { eq[ci][j2 + 1] = eq[ci][j2]; --j2; }
                eq[ci][j2 + 1] = key;
            }
            for (unsigned int i = 0; i < rem; ++i)
                sorted[ci][pos + i] = ((unsigned long long)T << 32) | (unsigned int)~eq[ci][i];
        } else {
            for (int j = 0; j < NTOT && rem > 0u; ++j)
                if (skey[ci][j] == T) {
                    sorted[ci][pos++] = ((unsigned long long)T << 32) | (unsigned int)~j;
                    --rem;
                }
        }
    }
    __syncthreads();

    // ---- phase 1c: bitonic sort 256 u64 ascending, shfl-based ----
    {
        unsigned long long v = sorted[ci][tl];
        #pragma unroll
        for (int k2 = 2; k2 <= 64; k2 <<= 1)
            v = bmerge_shfl(v, tl, k2, k2 >> 1);
        sorted[ci][tl] = v;
        __syncthreads();
        {
            unsigned long long o = sorted[ci][tl ^ 64];    // k2=128, j2=64
            bool km = (((tl & 128) == 0) == ((tl & 64) != 0));
            v = km ? (v > o ? v : o) : (v < o ? v : o);
            v = bmerge_shfl(v, tl, 128, 32);
        }
        __syncthreads();
        sorted[ci][tl] = v;
        __syncthreads();
        {
            unsigned long long o = sorted[ci][tl ^ 128];   // k2=256, j2=128
            bool km = ((tl & 128) != 0);
            v = km ? (v > o ? v : o) : (v < o ? v : o);
        }
        __syncthreads();
        sorted[ci][tl] = v;
        __syncthreads();
        {
            unsigned long long o = sorted[ci][tl ^ 64];    // k2=256, j2=64..1
            bool km = ((tl & 64) != 0);
            v = km ? (v > o ? v : o) : (v < o ? v : o);
            v = bmerge_shfl(v, tl, 256, 32);
        }
        __syncthreads();
        sorted[ci][tl] = v;
        __syncthreads();
    }

    // ---- phase 2: chunked greedy NMS, one wave per class ----
    if (tl < 64) {                       // wave 0 (ci=0) / wave 4 (ci=1)
        int lane = tl;
        int outPos = 0;
        for (int chunk = 0; chunk < SSEL / 64 && outPos < TOPK; ++chunk) {
            unsigned long long key = sorted[ci][SSEL - 1 - (chunk * 64 + lane)];
            unsigned int j = ~(unsigned int)key;
            float sc = unorderable((unsigned int)(key >> 32));
            float4 bj = bsrc[j];
            cbox[ci][lane] = bj;
            float amine = (bj.z - bj.x) * (bj.w - bj.y);

            bool sup = false;
            for (int t2 = 0; t2 < outPos; ++t2) {
                float4 wb = abox[ci][t2];
                float a1 = (wb.z - wb.x) * (wb.w - wb.y);
                float yy1 = fmaxf(wb.x, bj.x);
                float xx1 = fmaxf(wb.y, bj.y);
                float yy2 = fminf(wb.z, bj.z);
                float xx2 = fminf(wb.w, bj.w);
                float inter = fmaxf(yy2 - yy1, 0.f) * fmaxf(xx2 - xx1, 0.f);
                float denom = a1 + amine - inter + 1e-9f;
                sup = sup || ((double)inter > MID05 * (double)denom);
            }

            unsigned long long supmask = 0ull;
            #pragma unroll 8
            for (int j2 = 0; j2 < 64; ++j2) {
                float4 wb = cbox[ci][j2];
                float a1 = (wb.z - wb.x) * (wb.w - wb.y);
                float yy1 = fmaxf(wb.x, bj.x);
                float xx1 = fmaxf(wb.y, bj.y);
                float yy2 = fminf(wb.z, bj.z);
                float xx2 = fminf(wb.w, bj.w);
                float inter = fmaxf(yy2 - yy1, 0.f) * fmaxf(xx2 - xx1, 0.f);
                float denom = a1 + amine - inter + 1e-9f;
                bool s2 = ((double)inter > MID05 * (double)denom);
                if (s2 && j2 < lane) supmask |= (1ull << j2);
            }

            unsigned long long cand = __ballot(!sup);
            unsigned long long accbits = 0ull;
            while (cand) {
                int i = __builtin_ctzll(cand);
                accbits |= (1ull << i);
                cand &= ~(1ull << i);
                unsigned long long row = __ballot((supmask >> i) & 1ull);
                cand &= ~row;
            }

            int nAcc = (int)__builtin_popcountll(accbits);
            int avail = TOPK - outPos;
            bool mine = (accbits >> lane) & 1ull;
            int myrank = (int)__builtin_popcountll(accbits & ((1ull << lane) - 1ull));
            if (mine && myrank < avail) {
                int pos = outPos + myrank;
                osc[pos] = sc;
                oid[pos] = (int)j;
                abox[ci][pos] = bj;
            }
            outPos += (nAcc < avail) ? nAcc : avail;
            __builtin_amdgcn_s_waitcnt(0);
        }
        if (lane == 0) s_outPos[ci] = outPos;
    }
    __syncthreads();

    // ---- phase 3: fallback continuation, block-uniform per class
    // (practically never taken; barrier-safe) ----
    for (int ci2 = 0; ci2 < 2; ++ci2) {
        int outPos = s_outPos[ci2];
        if (outPos < TOPK) {
            int c2 = pair * 2 + ci2;
            float* osc2 = nms_score + ((size_t)b * NCLS + c2) * TOPK;
            int*   oid2 = nms_idx   + ((size_t)b * NCLS + c2) * TOPK;
            if (t < SSEL) skey[ci2][~(unsigned int)sorted[ci2][t]] = 0u;
            __syncthreads();
            for (int j = t; j < NTOT; j += 512) {
                unsigned int u = skey[ci2][j];
                if (!u) continue;
                float4 bj = bsrc[j];
                float amine = (bj.z - bj.x) * (bj.w - bj.y);
                bool sup = false;
                for (int t2 = 0; t2 < outPos; ++t2) {
                    float4 wb = abox[ci2][t2];
                    float a1 = (wb.z - wb.x) * (wb.w - wb.y);
                    float yy1 = fmaxf(wb.x, bj.x);
                    float xx1 = fmaxf(wb.y, bj.y);
                    float yy2 = fminf(wb.z, bj.z);
                    float xx2 = fminf(wb.w, bj.w);
                    float inter = fmaxf(yy2 - yy1, 0.f) * fmaxf(xx2 - xx1, 0.f);
                    float denom = a1 + amine - inter + 1e-9f;
                    sup = sup || ((double)inter > MID05 * (double)denom);
                }
                if (sup) skey[ci2][j] = 0u;
            }
            __syncthreads();
            while (outPos < TOPK) {
                if (t == 0) s_m[ci2] = 0ull;
                __syncthreads();
                unsigned long long loc = 0ull;
                for (int j = t; j < NTOT; j += 512) {
                    unsigned int u = skey[ci2][j];
                    if (u) {
                        unsigned long long kk = ((unsigned long long)u << 32) | (unsigned int)~j;
                        loc = (kk > loc) ? kk : loc;
                    }
                }
                atomicMax(&s_m[ci2], loc);
                __syncthreads();
                unsigned long long m = s_m[ci2];
                if ((long long)m >= 0) break;
                unsigned int wi = ~(unsigned int)m;
                float4 wb = bsrc[wi];
                if (t == 0) {
                    osc2[outPos] = unorderable((unsigned int)(m >> 32));
                    oid2[outPos] = (int)wi;
                    skey[ci2][wi] = 0u;
                }
                __syncthreads();
                float a1 = (wb.z - wb.x) * (wb.w - wb.y);
                for (int j = t; j < NTOT; j += 512) {
                    unsigned int u = skey[ci2][j];
                    if (!u) continue;
                    float4 bj = bsrc[j];
                    float yy1 = fmaxf(wb.x, bj.x);
                    float xx1 = fmaxf(wb.y, bj.y);
                    float yy2 = fminf(wb.z, bj.z);
                    float xx2 = fminf(wb.w, bj.w);
                    float inter = fmaxf(yy2 - yy1, 0.f) * fmaxf(xx2 - xx1, 0.f);
                    float a2 = (bj.z - bj.x) * (bj.w - bj.y);
                    float denom = a1 + a2 - inter + 1e-9f;
                    if ((double)inter > MID05 * (double)denom) skey[ci2][j] = 0u;
                }
                ++outPos;
                __syncthreads();
            }
            if (t == 0) s_outPos[ci2] = outPos;
            __syncthreads();
        }
    }

    {   // tail fill per class
        int op = s_outPos[ci];
        for (int k2 = op + tl; k2 < TOPK; k2 += 256) { osc[k2] = -INFINITY; oid[k2] = 0; }
    }

    // ---- epilogue gate: last of the batch's 10 blocks runs final top-100 ----
    __syncthreads();              // drains this block's global writes
    if (t == 0) {
        __threadfence();          // release our batch slice
        int old = atomicAdd(&cnt[b], 1);
        s_last = (old == 9) ? 1 : 0;
        if (s_last) __threadfence();   // acquire
    }
    __syncthreads();
    if (!s_last) return;

    // ---- final top-100 (round-12-verified logic; 512-thread strides) ----
    for (int f = t; f < 2000; f += 512) {
        float s = nms_score[(size_t)b * 2000 + f];
        float v = isfinite(s) ? s : -1.0f;
        skey[0][f] = orderable(v);
    }
    if (t == 0) { s_kk[0] = TOPK; s_prefix[0] = 0u; s_cnt[0] = 0u; s_eqcnt[0] = 0u; }
    if (t < 128) sorted[0][t] = 0ull;
    __syncthreads();

    for (int pass = 0; pass < 4; ++pass) {
        int shift = 24 - 8 * pass;
        unsigned int prefix = s_prefix[0], kk = s_kk[0];
        if (t < 256) hist[0][t] = 0u;
        __syncthreads();
        for (int f = t; f < 2000; f += 512) {
            unsigned int u = skey[0][f];
            if (pass == 0 || (u >> (shift + 8)) == prefix)
                atomicAdd(&hist[0][(u >> shift) & 255u], 1u);
        }
        __syncthreads();
        if (t < 64) radix_pass_scan(hist[0], &s_prefix[0], &s_kk[0], prefix, kk, t);
        __syncthreads();
    }

    unsigned int Tf = s_prefix[0];
    for (int f = t; f < 2000; f += 512) {
        unsigned int u = skey[0][f];
        if (u > Tf) {
            unsigned int pos = atomicAdd(&s_cnt[0], 1u);
            sorted[0][pos] = ((unsigned long long)u << 32) | (unsigned int)~f;
        } else if (u == Tf) {
            unsigned int p = atomicAdd(&s_eqcnt[0], 1u);
            if (p < 128u) eq[0][p] = f;
        }
    }
    __syncthreads();
    if (t == 0) {
        unsigned int pos = s_cnt[0];
        unsigned int rem = s_kk[0];
        unsigned int cnt2 = s_eqcnt[0];
        if (cnt2 <= 128u) {
            for (unsigned int i = 1; i < cnt2; ++i) {
                int key = eq[0][i]; int j2 = (int)i - 1;
                while (j2 >= 0 && eq[0][j2] > key) { eq[0][j2 + 1] = eq[0][j2]; --j2; }
                eq[0][j2 + 1] = key;
            }
            for (unsigned int i = 0; i < rem; ++i)
                sorted[0][pos + i] = ((unsigned long long)Tf << 32) | (unsigned int)~eq[0][i];
        } else {
            for (int f = 0; f < 2000 && rem > 0u; ++f)
                if (skey[0][f] == Tf) {
                    sorted[0][pos++] = ((unsigned long long)Tf << 32) | (unsigned int)~f;
                    --rem;
                }
        }
    }
    __syncthreads();

    {   // bitonic sort 128 u64 ascending, shfl-based (zeros sink)
        unsigned long long v = (t < 128) ? sorted[0][t] : 0ull;
        if (t < 128) {
            #pragma unroll
            for (int k2 = 2; k2 <= 64; k2 <<= 1)
                v = bmerge_shfl(v, t, k2, k2 >> 1);
            sorted[0][t] = v;
        }
        __syncthreads();
        if (t < 128) {
            unsigned long long o = sorted[0][t ^ 64];    // k2=128, j2=64
            bool km = ((t & 64) != 0);
            v = km ? (v > o ? v : o) : (v < o ? v : o);
            v = bmerge_shfl(v, t, 128, 32);
        }
        __syncthreads();
        if (t < 128) sorted[0][t] = v;
        __syncthreads();
    }

    if (t < TOPK) {
        unsigned long long kk = sorted[0][127 - t];    // t-th largest
        float v = unorderable((unsigned int)(kk >> 32));
        int fi = (int)~(unsigned int)kk;
        float* o = outbuf + ((size_t)b * TOPK + t) * 6;
        if (v > 0.3f) {
            int bidx = nms_idx[(size_t)b * 2000 + fi];
            float4 bxw = ((const float4*)boxes_all)[(size_t)b * NTOT + bidx];
            o[0] = bxw.x; o[1] = bxw.y; o[2] = bxw.z; o[3] = bxw.w;
            o[4] = v; o[5] = (float)(fi / TOPK);
        } else {
            o[0] = 0.f; o[1] = 0.f; o[2] = 0.f; o[3] = 0.f; o[4] = 0.f; o[5] = 0.f;
        }
    }
}

extern "C" void kernel_launch(void* const* d_in, const int* in_sizes, int n_in,
                              void* d_out, int out_size, void* d_ws, size_t ws_size,
                              hipStream_t stream) {
    (void)out_size; (void)ws_size;
    const float* cls[3] = {nullptr, nullptr, nullptr};
    const float* bbx[3] = {nullptr, nullptr, nullptr};
    for (int i = 0; i < n_in; ++i) {
        const float* p = (const float*)d_in[i];
        switch (in_sizes[i]) {
            case 16 * 6400 * 20: cls[0] = p; break;
            case 16 * 6400 * 32: bbx[0] = p; break;
            case 16 * 1600 * 20: cls[1] = p; break;
            case 16 * 1600 * 32: bbx[1] = p; break;
            case 16 *  400 * 20: cls[2] = p; break;
            case 16 *  400 * 32: bbx[2] = p; break;
            default: break;  // origin_shapes (unused by reference)
        }
    }

    char* w = (char*)d_ws;
    int*   sel_idx    = (int*)(w);                       // 128000 B used
    float* boxes_all  = (float*)(w + 131072);            // 614400 B
    float* scores_t   = (float*)(w + 745472);            // 3072000 B
    unsigned int* keys0 = (unsigned int*)(w + 745472);           // aliased (dies pre-decode)
    unsigned int* keys1 = (unsigned int*)(w + 745472 + 409600);
    float* nms_score  = (float*)(w + 3817472);           // 128000 B
    int*   nms_idx    = (int*)(w + 3945472);             // 128000 B
    int*   cnt        = (int*)(w + 4073472);             // 64 B -> total 4073536 B

    hipLaunchKernelGGL(compute_keys_kernel, dim3((BATCH * (N0 + N1) + 255) / 256), dim3(256), 0, stream,
                       cls[0], cls[1], keys0, keys1, cnt);
    hipLaunchKernelGGL(radix_select_kernel, dim3(32), dim3(256), 0, stream,
                       keys0, keys1, sel_idx);
    hipLaunchKernelGGL(decode_kernel, dim3((BATCH * NTOT + 255) / 256), dim3(256), 0, stream,
                       cls[0], cls[1], cls[2], bbx[0], bbx[1], bbx[2],
                       sel_idx, boxes_all, scores_t);
    hipLaunchKernelGGL(class_nms_kernel, dim3(BATCH * NCLS / 2), dim3(512), 0, stream,
                       boxes_all, scores_t, nms_score, nms_idx, cnt, (float*)d_out);
}